// Round 3
// baseline (771.740 us; speedup 1.0000x reference)
//
#include <hip/hip_runtime.h>

typedef short bf16x8 __attribute__((ext_vector_type(8)));
typedef float f32x4  __attribute__((ext_vector_type(4)));

static __device__ __forceinline__ unsigned short f2bf(float f) {
    unsigned int u = __builtin_bit_cast(unsigned int, f);
    u += 0x7FFFu + ((u >> 16) & 1u);   // round-to-nearest-even
    return (unsigned short)(u >> 16);
}

// ---------------- Kernel 1: demodulate + convert weights to bf16 -------------
// out layout: wn[((tap*4 + ci_chunk)*128 + co)*32 + ci_in_chunk]  (bf16 bits)
__global__ __launch_bounds__(256) void prep_w_k(const float* __restrict__ w,
                                                unsigned short* __restrict__ wn) {
    const int co = blockIdx.x;
    const int t  = threadIdx.x;
    const float* wc = w + co * 3456;
    float s = 0.f;
    for (int i = t; i < 3456; i += 256) { float v = wc[i]; s += v * v; }
#pragma unroll
    for (int off = 32; off; off >>= 1) s += __shfl_down(s, off);
    __shared__ float red[4];
    __shared__ float dsh;
    if ((t & 63) == 0) red[t >> 6] = s;
    __syncthreads();
    if (t == 0) dsh = rsqrtf(red[0] + red[1] + red[2] + red[3] + 1e-8f);
    __syncthreads();
    const float d = dsh;
    for (int i = t; i < 3456; i += 256) {
        int ci = i / 27, tap = i - ci * 27;
        float v = wc[i] * d;
        wn[((tap * 4 + (ci >> 5)) * 128 + co) * 32 + (ci & 31)] = f2bf(v);
    }
}

// ---------------- Kernel 2: implicit-GEMM conv3d, pipelined ------------------
// 512 thr = 8 waves (4 d-slices x 2 co-halves). Tile M=512 (d4,h4,w32), N=128.
// LDS: DOUBLE-buffered halo, plane-major: [buf2][ci_plane4][pos1224] x 16B.
//   plane stride 9800 shorts (19600B -> bank shift 4/plane). Total 156800 B.
// Pipeline: xf/wf fragments prefetched one tap ahead (regs); staging of chunk
//   c+1 strip-mined into taps 17..26 of chunk c (loads tap j, ds_write tap j+1).
//   One __syncthreads per chunk.
#define PL   9800
#define BUFS 39200
__global__ __launch_bounds__(512, 2) void conv3d_k(
    const float* __restrict__ x, const unsigned short* __restrict__ wn,
    const float* __restrict__ bias, float* __restrict__ out) {
    __shared__ __align__(16) unsigned short lds[2 * BUFS];   // 156800 B
    float* ldsf = reinterpret_cast<float*>(lds);

    const int t    = threadIdx.x;
    const int lane = t & 63;
    const int wid  = t >> 6;
    const int wr   = wid >> 1;     // 0..3 : d-slice of tile
    const int wcn  = wid & 1;      // 0..1 : co half
    const int ll   = lane & 15;
    const int g    = lane >> 4;    // 0..3 : k-group

    const int bid = blockIdx.x;
    const int b  = bid >> 6;
    const int dt = (bid >> 3) & 7, ht = bid & 7;
    const int d0 = dt * 4, h0 = ht * 4;

    // staging constants
    const int sw  = t & 31;          // w
    const int sg  = (t >> 5) & 3;    // ci plane (8 ci)
    const int rhi = t >> 7;          // 0..3

    f32x4 acc[8][4];
#pragma unroll
    for (int i = 0; i < 8; ++i)
#pragma unroll
        for (int j = 0; j < 4; ++j) acc[i][j] = (f32x4){0.f, 0.f, 0.f, 0.f};

    float bv[4][4];
#pragma unroll
    for (int nf = 0; nf < 4; ++nf) {
        f32x4 bb = *(const f32x4*)&bias[wcn * 64 + nf * 16 + g * 4];
#pragma unroll
        for (int q = 0; q < 4; ++q) bv[nf][q] = bb[q];
    }

    // zero the w-edge columns (wx==0, wx==33) in BOTH buffers, all planes
    if (t < 288) {
        int pi  = t >> 2;                 // 0..71
        int row = pi >> 1;                // 0..35
        int pos = row * 34 + (pi & 1) * 33;
        int sgz = t & 3;
        bf16x8 z = {0, 0, 0, 0, 0, 0, 0, 0};
        *(bf16x8*)&lds[sgz * PL + pos * 8] = z;
        *(bf16x8*)&lds[BUFS + sgz * PL + pos * 8] = z;
    }

    // ---- prologue: stage chunk 0 halo into buffer 0 ----
#pragma unroll
    for (int p = 0; p < 9; ++p) {
        int rowid = p * 4 + rhi;               // 0..35
        int pd = (rowid * 43) >> 8;            // /6
        int ph = rowid - pd * 6;
        int d = d0 - 1 + pd, h = h0 - 1 + ph;
        bool ok = ((unsigned)d < 32u) && ((unsigned)h < 32u);
        const float* src = x + (((b * 128 + sg * 8) * 32 + d) * 32 + h) * 32 + sw;
        float v[8];
#pragma unroll
        for (int j = 0; j < 8; ++j) v[j] = ok ? src[j * 32768] : 0.f;
        bf16x8 pk;
#pragma unroll
        for (int j = 0; j < 8; ++j) pk[j] = (short)f2bf(v[j]);
        *(bf16x8*)&lds[sg * PL + (rowid * 34 + sw + 1) * 8] = pk;
    }
    __syncthreads();

    for (int c = 0; c < 4; ++c) {
        const int buf  = (c & 1) * BUFS;
        const int bufn = BUFS - buf;
        const bool more = (c < 3);
        const unsigned short* wbase = wn + c * 4096 + ((wcn * 64 + ll) * 32 + g * 8);
        const int xbase = buf + g * PL;

        // tap-0 fragments
        bf16x8 xf[8], wf[4];
#pragma unroll
        for (int mf = 0; mf < 8; ++mf) {
            int pos = (wr * 6 + (mf >> 1)) * 34 + (mf & 1) * 16 + ll;
            xf[mf] = *(const bf16x8*)&lds[xbase + pos * 8];
        }
#pragma unroll
        for (int nf = 0; nf < 4; ++nf)
            wf[nf] = *(const bf16x8*)&wbase[nf * 512];

        float sf[2][8];   // staging regs, statically indexed under full unroll

#pragma unroll
        for (int tap = 0; tap < 27; ++tap) {
            // ---- prefetch next tap's fragments (regs) ----
            bf16x8 xfn[8], wfn[4];
            if (tap < 26) {
                const int odn = (tap + 1) / 9, ohn = ((tap + 1) / 3) % 3, own = (tap + 1) % 3;
#pragma unroll
                for (int mf = 0; mf < 8; ++mf) {
                    int pos = ((wr + odn) * 6 + (mf >> 1) + ohn) * 34 +
                              (mf & 1) * 16 + ll + own;
                    xfn[mf] = *(const bf16x8*)&lds[xbase + pos * 8];
                }
#pragma unroll
                for (int nf = 0; nf < 4; ++nf)
                    wfn[nf] = *(const bf16x8*)&wbase[(tap + 1) * 16384 + nf * 512];
            }

            // ---- strip-mined staging of chunk c+1 (issue early, write late) --
            if (more && tap >= 17 && tap < 26) {       // issue loads, j = tap-17
                const int j = tap - 17;
                int rowid = j * 4 + rhi;
                int pd = (rowid * 43) >> 8;
                int ph = rowid - pd * 6;
                int d = d0 - 1 + pd, h = h0 - 1 + ph;
                bool ok = ((unsigned)d < 32u) && ((unsigned)h < 32u);
                const float* src = x + (((b * 128 + (c + 1) * 32 + sg * 8) * 32 + d) * 32 + h) * 32 + sw;
                float* S = sf[j & 1];
#pragma unroll
                for (int jj = 0; jj < 8; ++jj) S[jj] = ok ? src[jj * 32768] : 0.f;
            }
            if (more && tap >= 18) {                   // convert+write, j = tap-18
                const int j = tap - 18;
                int rowid = j * 4 + rhi;
                const float* S = sf[j & 1];
                bf16x8 pk;
#pragma unroll
                for (int jj = 0; jj < 8; ++jj) pk[jj] = (short)f2bf(S[jj]);
                *(bf16x8*)&lds[bufn + sg * PL + (rowid * 34 + sw + 1) * 8] = pk;
            }

            // ---- MFMA cluster ----
#pragma unroll
            for (int mf = 0; mf < 8; ++mf)
#pragma unroll
                for (int nf = 0; nf < 4; ++nf)
                    acc[mf][nf] = __builtin_amdgcn_mfma_f32_16x16x32_bf16(
                        wf[nf], xf[mf], acc[mf][nf], 0, 0, 0);

            if (tap < 26) {
#pragma unroll
                for (int mf = 0; mf < 8; ++mf) xf[mf] = xfn[mf];
#pragma unroll
                for (int nf = 0; nf < 4; ++nf) wf[nf] = wfn[nf];
            }
        }
        __syncthreads();   // halo buf c fully consumed; buf c+1 fully written
    }

    // ---- epilogue: bias + lrelu + gain + clamp; LDS-transposed 128B stores --
#pragma unroll
    for (int h = 0; h < 4; ++h) {
        __syncthreads();
#pragma unroll
        for (int whalf = 0; whalf < 2; ++whalf) {
            const int mf = h * 2 + whalf;
#pragma unroll
            for (int nf = 0; nf < 4; ++nf) {
#pragma unroll
                for (int q = 0; q < 4; ++q) {
                    const int co = wcn * 64 + nf * 16 + g * 4 + q;
                    float v = acc[mf][nf][q] + bv[nf][q];
                    v = v > 0.f ? v : v * 0.2f;
                    v *= 1.41421356237f;
                    v = fminf(fmaxf(v, -256.f), 256.f);
                    ldsf[(co * 4 + wr) * 33 + whalf * 16 + ll] = v;
                }
            }
        }
        __syncthreads();
#pragma unroll
        for (int it = 0; it < 8; ++it) {
            const int row = it * 64 + (t >> 3);     // 0..511 = co*4 + wr
            const int ls  = t & 7;
            f32x4 v = *(f32x4*)&ldsf[row * 33 + ls * 4];
            const int co = row >> 2, wr2 = row & 3;
            *(f32x4*)&out[(size_t)(b * 128 + co) * 32768 +
                          (d0 + wr2) * 1024 + (h0 + h) * 32 + ls * 4] = v;
        }
    }
}

extern "C" void kernel_launch(void* const* d_in, const int* in_sizes, int n_in,
                              void* d_out, int out_size, void* d_ws, size_t ws_size,
                              hipStream_t stream) {
    const float* x    = (const float*)d_in[0];
    const float* w    = (const float*)d_in[1];
    const float* bias = (const float*)d_in[2];
    float* out        = (float*)d_out;
    unsigned short* wn = (unsigned short*)d_ws;   // 27*128*128 bf16 = 884736 B

    prep_w_k<<<128, 256, 0, stream>>>(w, wn);
    conv3d_k<<<512, 512, 0, stream>>>(x, wn, bias, out);
}

// Round 4
// 477.164 us; speedup vs baseline: 1.6173x; 1.6173x over previous
//
#include <hip/hip_runtime.h>

typedef short bf16x8 __attribute__((ext_vector_type(8)));
typedef float f32x4  __attribute__((ext_vector_type(4)));

static __device__ __forceinline__ unsigned short f2bf(float f) {
    unsigned int u = __builtin_bit_cast(unsigned int, f);
    u += 0x7FFFu + ((u >> 16) & 1u);   // round-to-nearest-even
    return (unsigned short)(u >> 16);
}

// ---------------- Kernel 1: demodulate + convert weights to bf16 -------------
// out layout: wn[((tap*4 + ci_chunk)*128 + co)*32 + ci_in_chunk]  (bf16 bits)
__global__ __launch_bounds__(256) void prep_w_k(const float* __restrict__ w,
                                                unsigned short* __restrict__ wn) {
    const int co = blockIdx.x;
    const int t  = threadIdx.x;
    const float* wc = w + co * 3456;
    float s = 0.f;
    for (int i = t; i < 3456; i += 256) { float v = wc[i]; s += v * v; }
#pragma unroll
    for (int off = 32; off; off >>= 1) s += __shfl_down(s, off);
    __shared__ float red[4];
    __shared__ float dsh;
    if ((t & 63) == 0) red[t >> 6] = s;
    __syncthreads();
    if (t == 0) dsh = rsqrtf(red[0] + red[1] + red[2] + red[3] + 1e-8f);
    __syncthreads();
    const float d = dsh;
    for (int i = t; i < 3456; i += 256) {
        int ci = i / 27, tap = i - ci * 27;
        float v = wc[i] * d;
        wn[((tap * 4 + (ci >> 5)) * 128 + co) * 32 + (ci & 31)] = f2bf(v);
    }
}

// ---------------- Kernel 2: implicit-GEMM conv3d, occupancy-first ------------
// 256 thr = 4 waves (2 d-halves x 2 co-halves). Tile M=128 (d2,h2,w32), N=128.
// Wave tile 64x64 -> acc = 16 f32x4 = 64 AGPR; target 4 waves/SIMD + 4 blk/CU
// (LDS 34.8 KB). Latency hidden by TLP across 4 phase-staggered blocks/CU.
// LDS halo: 544 pos (16 rows x 34 w) x 32ci bf16, XOR slot swizzle (R1-proven).
#define NPOS 544
__global__ __launch_bounds__(256, 4) void conv3d_k(
    const float* __restrict__ x, const unsigned short* __restrict__ wn,
    const float* __restrict__ bias, float* __restrict__ out) {
    __shared__ __align__(16) unsigned short lds[NPOS * 32];   // 34816 B
    float* ldsf = reinterpret_cast<float*>(lds);

    const int t    = threadIdx.x;
    const int lane = t & 63;
    const int wid  = t >> 6;       // 0..3
    const int wr   = wid >> 1;     // 0..1 : d-half of tile
    const int wcn  = wid & 1;      // 0..1 : co half
    const int ll   = lane & 15;
    const int g    = lane >> 4;    // 0..3 : k-group

    const int bid = blockIdx.x;
    const int b  = bid >> 8;                  // 8 batches
    const int dt = (bid >> 4) & 15, ht = bid & 15;
    const int d0 = dt * 2, h0 = ht * 2;

    // staging constants
    const int sw  = t & 31;          // w
    const int sg  = (t >> 5) & 3;    // ci plane (8 ci)
    const int rhi = t >> 7;          // 0..1

    f32x4 acc[4][4];
#pragma unroll
    for (int i = 0; i < 4; ++i)
#pragma unroll
        for (int j = 0; j < 4; ++j) acc[i][j] = (f32x4){0.f, 0.f, 0.f, 0.f};

    float bv[4][4];
#pragma unroll
    for (int nf = 0; nf < 4; ++nf) {
        f32x4 bb = *(const f32x4*)&bias[wcn * 64 + nf * 16 + g * 4];
#pragma unroll
        for (int q = 0; q < 4; ++q) bv[nf][q] = bb[q];
    }

    // zero the w-edge columns (wx==0, wx==33), all 4 slots: 32 pos x 4 slots
    if (t < 128) {
        int pi  = t >> 2;                 // 0..31
        int row = pi >> 1;                // 0..15
        int pos = row * 34 + (pi & 1) * 33;
        bf16x8 z = {0, 0, 0, 0, 0, 0, 0, 0};
        *(bf16x8*)&lds[pos * 32 + (t & 3) * 8] = z;
    }

    for (int c = 0; c < 4; ++c) {
        if (c) __syncthreads();          // halo of chunk c-1 fully consumed
        // ---- stage x halo chunk (w-major global -> ci-major swizzled LDS) ----
#pragma unroll
        for (int p = 0; p < 8; ++p) {
            int rowid = p * 2 + rhi;               // 0..15
            int pd = rowid >> 2, ph = rowid & 3;
            int d = d0 - 1 + pd, h = h0 - 1 + ph;
            bool ok = ((unsigned)d < 32u) && ((unsigned)h < 32u);
            const float* src = x + (((b * 128 + c * 32 + sg * 8) * 32 + d) * 32 + h) * 32 + sw;
            float v[8];
#pragma unroll
            for (int j = 0; j < 8; ++j) v[j] = ok ? src[j * 32768] : 0.f;
            bf16x8 pk;
#pragma unroll
            for (int j = 0; j < 8; ++j) pk[j] = (short)f2bf(v[j]);
            int pos = rowid * 34 + sw + 1;
            int slot = sg ^ ((pos >> 1) & 3);
            *(bf16x8*)&lds[pos * 32 + slot * 8] = pk;
        }
        __syncthreads();

        // ---- 27 taps, barrier-free; weights direct from global (L1/L2-hit) --
        const unsigned short* wbase = wn + c * 4096 + ((wcn * 64 + ll) * 32 + g * 8);
        bf16x8 wf[4];
#pragma unroll
        for (int nf = 0; nf < 4; ++nf)
            wf[nf] = *(const bf16x8*)&wbase[nf * 512];

#pragma unroll
        for (int tap = 0; tap < 27; ++tap) {
            const int od = tap / 9, oh = (tap / 3) % 3, ow = tap % 3;
            bf16x8 wfn[4];
            if (tap < 26) {
#pragma unroll
                for (int nf = 0; nf < 4; ++nf)
                    wfn[nf] = *(const bf16x8*)&wbase[(tap + 1) * 16384 + nf * 512];
            }
            bf16x8 xf[4];
#pragma unroll
            for (int mf = 0; mf < 4; ++mf) {
                int pos = ((wr + od) * 4 + (mf >> 1) + oh) * 34 +
                          (mf & 1) * 16 + ll + ow;
                int slot = g ^ ((pos >> 1) & 3);
                xf[mf] = *(const bf16x8*)&lds[pos * 32 + slot * 8];
            }
            __builtin_amdgcn_s_setprio(1);
#pragma unroll
            for (int mf = 0; mf < 4; ++mf)
#pragma unroll
                for (int nf = 0; nf < 4; ++nf)
                    acc[mf][nf] = __builtin_amdgcn_mfma_f32_16x16x32_bf16(
                        wf[nf], xf[mf], acc[mf][nf], 0, 0, 0);
            __builtin_amdgcn_s_setprio(0);
            if (tap < 26) {
#pragma unroll
                for (int nf = 0; nf < 4; ++nf) wf[nf] = wfn[nf];
            }
        }
    }

    // ---- epilogue: bias + lrelu + gain + clamp; LDS-transposed 128B stores --
    // 4 passes, one per output row (dd,hh): lds [co128][33] f32 = 16.9 KB
#pragma unroll
    for (int p = 0; p < 4; ++p) {
        const int dd = p >> 1, hh = p & 1;
        __syncthreads();
        if (wr == dd) {
#pragma unroll
            for (int whalf = 0; whalf < 2; ++whalf) {
                const int mf = hh * 2 + whalf;
#pragma unroll
                for (int nf = 0; nf < 4; ++nf) {
#pragma unroll
                    for (int q = 0; q < 4; ++q) {
                        const int co = wcn * 64 + nf * 16 + g * 4 + q;
                        float v = acc[mf][nf][q] + bv[nf][q];
                        v = v > 0.f ? v : v * 0.2f;
                        v *= 1.41421356237f;
                        v = fminf(fmaxf(v, -256.f), 256.f);
                        ldsf[co * 33 + whalf * 16 + ll] = v;
                    }
                }
            }
        }
        __syncthreads();
#pragma unroll
        for (int it = 0; it < 4; ++it) {
            const int row = it * 32 + (t >> 3);     // co 0..127
            const int ls  = t & 7;
            f32x4 v = *(f32x4*)&ldsf[row * 33 + ls * 4];
            *(f32x4*)&out[(size_t)(b * 128 + row) * 32768 +
                          (d0 + dd) * 1024 + (h0 + hh) * 32 + ls * 4] = v;
        }
    }
}

extern "C" void kernel_launch(void* const* d_in, const int* in_sizes, int n_in,
                              void* d_out, int out_size, void* d_ws, size_t ws_size,
                              hipStream_t stream) {
    const float* x    = (const float*)d_in[0];
    const float* w    = (const float*)d_in[1];
    const float* bias = (const float*)d_in[2];
    float* out        = (float*)d_out;
    unsigned short* wn = (unsigned short*)d_ws;   // 27*128*128 bf16 = 884736 B

    prep_w_k<<<128, 256, 0, stream>>>(w, wn);
    conv3d_k<<<2048, 256, 0, stream>>>(x, wn, bias, out);
}

// Round 5
// 343.768 us; speedup vs baseline: 2.2449x; 1.3880x over previous
//
#include <hip/hip_runtime.h>

typedef short bf16x8 __attribute__((ext_vector_type(8)));
typedef float f32x4  __attribute__((ext_vector_type(4)));
typedef unsigned short u16;

static __device__ __forceinline__ u16 f2bf(float f) {
    unsigned int u = __builtin_bit_cast(unsigned int, f);
    u += 0x7FFFu + ((u >> 16) & 1u);   // round-to-nearest-even
    return (u16)(u >> 16);
}

static __device__ __forceinline__ void gload_lds16(const void* g, void* l) {
    __builtin_amdgcn_global_load_lds((const __attribute__((address_space(1))) void*)g,
                                     (__attribute__((address_space(3))) void*)l, 16, 0, 0);
}

// ---------------- Kernel 1: demodulate + convert weights to bf16 -------------
// wn[((tap*4 + cc)*128 + co)*32 + ci_in_chunk]  == kstep-major [k108][co128][ci32]
__global__ __launch_bounds__(256) void prep_w_k(const float* __restrict__ w,
                                                u16* __restrict__ wn) {
    const int co = blockIdx.x;
    const int t  = threadIdx.x;
    const float* wc = w + co * 3456;
    float s = 0.f;
    for (int i = t; i < 3456; i += 256) { float v = wc[i]; s += v * v; }
#pragma unroll
    for (int off = 32; off; off >>= 1) s += __shfl_down(s, off);
    __shared__ float red[4];
    __shared__ float dsh;
    if ((t & 63) == 0) red[t >> 6] = s;
    __syncthreads();
    if (t == 0) dsh = rsqrtf(red[0] + red[1] + red[2] + red[3] + 1e-8f);
    __syncthreads();
    const float d = dsh;
    for (int i = t; i < 3456; i += 256) {
        int ci = i / 27, tap = i - ci * 27;
        float v = wc[i] * d;
        wn[((tap * 4 + (ci >> 5)) * 128 + co) * 32 + (ci & 31)] = f2bf(v);
    }
}

// ---------------- Kernel 2: transpose x -> channels-grouped bf16 -------------
// xt[((b*16 + g)*32768 + d*1024 + h*32 + w)*8 + j] = bf16(x[b][g*8+j][d][h][w])
__global__ __launch_bounds__(256) void xpose_k(const float* __restrict__ x,
                                               u16* __restrict__ xt) {
    const int bid = blockIdx.x;
    const int b = bid >> 10, d = (bid >> 5) & 31, h = bid & 31;
    const int t = threadIdx.x;
    const int w = t & 31, cg = t >> 5;
    const int base_dhw = d * 1024 + h * 32 + w;
#pragma unroll
    for (int r = 0; r < 2; ++r) {
        int g = cg + r * 8;
        const float* src = x + ((size_t)(b * 128 + g * 8) << 15) + base_dhw;
        bf16x8 pk;
#pragma unroll
        for (int j = 0; j < 8; ++j) pk[j] = (short)f2bf(src[(size_t)j << 15]);
        *(bf16x8*)&xt[((size_t)((b * 16 + g) << 15) + base_dhw) * 8] = pk;
    }
}

// ---------------- Kernel 3: conv3d, async 2-phase pipelined GEMM -------------
// 512 thr = 8 waves (4 M-slices x 2 co-halves). Tile M=256 (d2,h4,w32), N=128.
// Wave tile 64x64 -> acc 64 regs; target 4 waves/SIMD = 2 blocks/CU (128 cap).
// LDS 48 KB: x dbuf 2x16KB (256 pos x 64B, source-swizzled), w dbuf 2x8KB.
// K-loop = 108 steps: STAGE(next, 3x global_load_lds) -> 8 ds_read -> 16 MFMA
// -> one __syncthreads (vmcnt0). 2 resident blocks stagger to cover drains.
#define KSX 1048576   // shorts: x-chain advance per k-step (4 groups * 32768 * 8)
#define KSW 4096      // shorts: wn advance per k-step
__global__ __launch_bounds__(512, 4) void conv_mx(
    const u16* __restrict__ wsb, const float* __restrict__ bias,
    float* __restrict__ out) {
    __shared__ __align__(16) u16 lds[24576];     // 49152 B
    const u16* xt = wsb + 524288;
    const u16* wn = wsb + 512;
    const u16* zp = wsb;                          // 16B zero page (memset)

    const int t = threadIdx.x, lane = t & 63, wid = t >> 6;
    const int ll = lane & 15, g = lane >> 4;
    const int mslice = wid >> 1, ncol = wid & 1;

    int wg = ((blockIdx.x & 7) << 7) | (blockIdx.x >> 3);   // XCD swizzle
    const int b = wg >> 7, dt = (wg >> 3) & 15, ht = wg & 7;
    const int d0 = dt * 2, h0 = ht * 4;

    // loop-invariant ds_read bases (shorts), swizzle folded in
    const int pos0 = mslice * 64 + ll;
    const int xro = pos0 * 32 + ((g ^ ((pos0 >> 1) & 3)) * 8);
    const int co0 = ncol * 64 + ll;
    const int wro = 16384 + co0 * 32 + ((g ^ ((co0 >> 1) & 3)) * 8);

    // staging lane constants (wave covers pos wid*32..wid*32+31 via 2 instrs)
    const int posA = wid * 32 + (lane >> 2);     // instr0; instr1 = posA+16
    const int slot = lane & 3;
    const int pdA = posA >> 7, phA = (posA >> 5) & 3, wA = posA & 31;  // wA 0..15
    const int gA = slot ^ ((posA >> 1) & 3);     // same for posA+16
    const int wco = wid * 16 + (lane >> 2);
    const u16* wsrc = wn + wco * 32 + ((slot ^ ((wco >> 1) & 3)) * 8);

    f32x4 acc[4][4];
#pragma unroll
    for (int i = 0; i < 4; ++i)
#pragma unroll
        for (int j = 0; j < 4; ++j) acc[i][j] = (f32x4){0.f, 0.f, 0.f, 0.f};

    const u16* xs0; bool okA, okB;
    const u16* xn0; bool nkA, nkB;

#define MKADDR(OD, OH, OW, A0, OA, OB) { \
    int Dx = d0 + pdA - 1 + (OD), Hx = h0 + phA - 1 + (OH), Wx = wA - 1 + (OW); \
    bool dh_ = ((unsigned)Dx < 32u) && ((unsigned)Hx < 32u); \
    OA = dh_ && ((unsigned)Wx < 32u); \
    OB = dh_ && (Wx < 16); \
    A0 = xt + (long)((b * 16 + gA) * 32768 + Dx * 1024 + Hx * 32 + Wx) * 8; }

#define STAGE(A0, OA, OB, PAR) { \
    gload_lds16(OA ? (const void*)(A0) : (const void*)zp, (void*)&lds[(PAR)*8192 + wid*1024]); \
    gload_lds16(OB ? (const void*)((A0) + 128) : (const void*)zp, (void*)&lds[(PAR)*8192 + wid*1024 + 512]); \
    gload_lds16((const void*)wsrc, (void*)&lds[16384 + (PAR)*4096 + wid*512]); \
    A0 += KSX; wsrc += KSW; }

#define FRAGMFMA(PAR) { \
    bf16x8 xf[4], wf[4]; \
    _Pragma("unroll") for (int mf = 0; mf < 4; ++mf) \
        xf[mf] = *(const bf16x8*)&lds[xro + (PAR)*8192 + mf*512]; \
    _Pragma("unroll") for (int nf = 0; nf < 4; ++nf) \
        wf[nf] = *(const bf16x8*)&lds[wro + (PAR)*4096 + nf*512]; \
    __builtin_amdgcn_s_setprio(1); \
    _Pragma("unroll") for (int mf = 0; mf < 4; ++mf) \
    _Pragma("unroll") for (int nf = 0; nf < 4; ++nf) \
        acc[mf][nf] = __builtin_amdgcn_mfma_f32_16x16x32_bf16(wf[nf], xf[mf], acc[mf][nf], 0, 0, 0); \
    __builtin_amdgcn_s_setprio(0); }

    // prologue: stage k-step 0 into buf0
    MKADDR(0, 0, 0, xs0, okA, okB);
    STAGE(xs0, okA, okB, 0);
    __syncthreads();

    for (int od = 0; od < 3; ++od)
    for (int oh = 0; oh < 3; ++oh)
    for (int ow = 0; ow < 3; ++ow) {
        const bool last = (od == 2) && (oh == 2) && (ow == 2);
        // cc0: read buf0, stage cc1 -> buf1
        STAGE(xs0, okA, okB, 1);
        FRAGMFMA(0);
        __syncthreads();
        // cc1: read buf1, stage cc2 -> buf0; compute next-tap addrs (overlapped)
        STAGE(xs0, okA, okB, 0);
        {
            int own = (ow < 2) ? ow + 1 : 0;
            int ohn = (ow < 2) ? oh : ((oh < 2) ? oh + 1 : 0);
            int odn = (ow < 2) ? od : ((oh < 2) ? od : od + 1);
            MKADDR(odn, ohn, own, xn0, nkA, nkB);
        }
        FRAGMFMA(1);
        __syncthreads();
        // cc2: read buf0, stage cc3 -> buf1
        STAGE(xs0, okA, okB, 1);
        FRAGMFMA(0);
        __syncthreads();
        // cc3: read buf1, stage next-tap k0 -> buf0
        if (!last) { STAGE(xn0, nkA, nkB, 0); }
        FRAGMFMA(1);
        __syncthreads();
        xs0 = xn0; okA = nkA; okB = nkB;   // xn already advanced to next cc1
    }

    // epilogue: bias + leaky_relu + sqrt(2) + clamp, direct stores
    const int pd = mslice >> 1, phb = (mslice & 1) * 2;
#pragma unroll
    for (int nf = 0; nf < 4; ++nf) {
        f32x4 bb = *(const f32x4*)&bias[ncol * 64 + nf * 16 + g * 4];
#pragma unroll
        for (int mf = 0; mf < 4; ++mf) {
            const int wq = (mf & 1) * 16 + ll;
            const int hh = h0 + phb + (mf >> 1);
            float* orow = out + ((size_t)(b * 128 + ncol * 64 + nf * 16 + g * 4) << 15)
                          + (d0 + pd) * 1024 + hh * 32 + wq;
#pragma unroll
            for (int q = 0; q < 4; ++q) {
                float v = acc[mf][nf][q] + bb[q];
                v = v > 0.f ? v : v * 0.2f;
                v *= 1.41421356237f;
                v = fminf(fmaxf(v, -256.f), 256.f);
                orow[(size_t)q << 15] = v;
            }
        }
    }
#undef MKADDR
#undef STAGE
#undef FRAGMFMA
}

// ---------------- Fallback conv (R4, proven) if ws too small -----------------
#define NPOS 544
__global__ __launch_bounds__(256, 4) void conv_fb(
    const float* __restrict__ x, const u16* __restrict__ wn,
    const float* __restrict__ bias, float* __restrict__ out) {
    __shared__ __align__(16) u16 lds[NPOS * 32];
    float* ldsf = reinterpret_cast<float*>(lds);
    const int t = threadIdx.x;
    const int lane = t & 63;
    const int wid  = t >> 6;
    const int wr   = wid >> 1;
    const int wcn  = wid & 1;
    const int ll   = lane & 15;
    const int g    = lane >> 4;
    const int bid = blockIdx.x;
    const int b  = bid >> 8;
    const int dt = (bid >> 4) & 15, ht = bid & 15;
    const int d0 = dt * 2, h0 = ht * 2;
    const int sw  = t & 31;
    const int sg  = (t >> 5) & 3;
    const int rhi = t >> 7;
    f32x4 acc[4][4];
#pragma unroll
    for (int i = 0; i < 4; ++i)
#pragma unroll
        for (int j = 0; j < 4; ++j) acc[i][j] = (f32x4){0.f, 0.f, 0.f, 0.f};
    float bv[4][4];
#pragma unroll
    for (int nf = 0; nf < 4; ++nf) {
        f32x4 bb = *(const f32x4*)&bias[wcn * 64 + nf * 16 + g * 4];
#pragma unroll
        for (int q = 0; q < 4; ++q) bv[nf][q] = bb[q];
    }
    if (t < 128) {
        int pi  = t >> 2;
        int row = pi >> 1;
        int pos = row * 34 + (pi & 1) * 33;
        bf16x8 z = {0, 0, 0, 0, 0, 0, 0, 0};
        *(bf16x8*)&lds[pos * 32 + (t & 3) * 8] = z;
    }
    for (int c = 0; c < 4; ++c) {
        if (c) __syncthreads();
#pragma unroll
        for (int p = 0; p < 8; ++p) {
            int rowid = p * 2 + rhi;
            int pd = rowid >> 2, ph = rowid & 3;
            int d = d0 - 1 + pd, h = h0 - 1 + ph;
            bool ok = ((unsigned)d < 32u) && ((unsigned)h < 32u);
            const float* src = x + (((b * 128 + c * 32 + sg * 8) * 32 + d) * 32 + h) * 32 + sw;
            float v[8];
#pragma unroll
            for (int j = 0; j < 8; ++j) v[j] = ok ? src[j * 32768] : 0.f;
            bf16x8 pk;
#pragma unroll
            for (int j = 0; j < 8; ++j) pk[j] = (short)f2bf(v[j]);
            int pos = rowid * 34 + sw + 1;
            int sl = sg ^ ((pos >> 1) & 3);
            *(bf16x8*)&lds[pos * 32 + sl * 8] = pk;
        }
        __syncthreads();
        const u16* wbase = wn + c * 4096 + ((wcn * 64 + ll) * 32 + g * 8);
        bf16x8 wf[4];
#pragma unroll
        for (int nf = 0; nf < 4; ++nf) wf[nf] = *(const bf16x8*)&wbase[nf * 512];
#pragma unroll
        for (int tap = 0; tap < 27; ++tap) {
            const int od = tap / 9, oh = (tap / 3) % 3, ow = tap % 3;
            bf16x8 wfn[4];
            if (tap < 26) {
#pragma unroll
                for (int nf = 0; nf < 4; ++nf)
                    wfn[nf] = *(const bf16x8*)&wbase[(tap + 1) * 16384 + nf * 512];
            }
            bf16x8 xf[4];
#pragma unroll
            for (int mf = 0; mf < 4; ++mf) {
                int pos = ((wr + od) * 4 + (mf >> 1) + oh) * 34 + (mf & 1) * 16 + ll + ow;
                int sl = g ^ ((pos >> 1) & 3);
                xf[mf] = *(const bf16x8*)&lds[pos * 32 + sl * 8];
            }
            __builtin_amdgcn_s_setprio(1);
#pragma unroll
            for (int mf = 0; mf < 4; ++mf)
#pragma unroll
                for (int nf = 0; nf < 4; ++nf)
                    acc[mf][nf] = __builtin_amdgcn_mfma_f32_16x16x32_bf16(
                        wf[nf], xf[mf], acc[mf][nf], 0, 0, 0);
            __builtin_amdgcn_s_setprio(0);
            if (tap < 26) {
#pragma unroll
                for (int nf = 0; nf < 4; ++nf) wf[nf] = wfn[nf];
            }
        }
    }
#pragma unroll
    for (int p = 0; p < 4; ++p) {
        const int dd = p >> 1, hh = p & 1;
        __syncthreads();
        if (wr == dd) {
#pragma unroll
            for (int whalf = 0; whalf < 2; ++whalf) {
                const int mf = hh * 2 + whalf;
#pragma unroll
                for (int nf = 0; nf < 4; ++nf) {
#pragma unroll
                    for (int q = 0; q < 4; ++q) {
                        const int co = wcn * 64 + nf * 16 + g * 4 + q;
                        float v = acc[mf][nf][q] + bv[nf][q];
                        v = v > 0.f ? v : v * 0.2f;
                        v *= 1.41421356237f;
                        v = fminf(fmaxf(v, -256.f), 256.f);
                        ldsf[co * 33 + whalf * 16 + ll] = v;
                    }
                }
            }
        }
        __syncthreads();
#pragma unroll
        for (int it = 0; it < 4; ++it) {
            const int row = it * 32 + (t >> 3);
            const int ls  = t & 7;
            f32x4 v = *(f32x4*)&ldsf[row * 33 + ls * 4];
            *(f32x4*)&out[(size_t)(b * 128 + row) * 32768 +
                          (d0 + dd) * 1024 + (h0 + hh) * 32 + ls * 4] = v;
        }
    }
}

extern "C" void kernel_launch(void* const* d_in, const int* in_sizes, int n_in,
                              void* d_out, int out_size, void* d_ws, size_t ws_size,
                              hipStream_t stream) {
    const float* x    = (const float*)d_in[0];
    const float* w    = (const float*)d_in[1];
    const float* bias = (const float*)d_in[2];
    float* out        = (float*)d_out;
    u16* wsb          = (u16*)d_ws;

    hipMemsetAsync(d_ws, 0, 1024, stream);                 // zero page
    prep_w_k<<<128, 256, 0, stream>>>(w, wsb + 512);       // wn at +1KB

    if (ws_size >= 68157440ull) {
        xpose_k<<<8192, 256, 0, stream>>>(x, wsb + 524288);  // xt at +1MB
        conv_mx<<<1024, 512, 0, stream>>>(wsb, bias, out);
    } else {
        conv_fb<<<2048, 256, 0, stream>>>(x, wsb + 512, bias, out);
    }
}

// Round 6
// 296.166 us; speedup vs baseline: 2.6058x; 1.1607x over previous
//
#include <hip/hip_runtime.h>

typedef short bf16x8 __attribute__((ext_vector_type(8)));
typedef float f32x4  __attribute__((ext_vector_type(4)));
typedef unsigned short u16;

static __device__ __forceinline__ u16 f2bf(float f) {
    unsigned int u = __builtin_bit_cast(unsigned int, f);
    u += 0x7FFFu + ((u >> 16) & 1u);   // round-to-nearest-even
    return (u16)(u >> 16);
}

static __device__ __forceinline__ void gload_lds16(const void* g, void* l) {
    __builtin_amdgcn_global_load_lds((const __attribute__((address_space(1))) void*)g,
                                     (__attribute__((address_space(3))) void*)l, 16, 0, 0);
}

// ---------------- Kernel 1: demodulate + convert weights to bf16 -------------
// wn[((tap*4 + cc)*128 + co)*32 + ci_in_chunk]  == kstep-major [k108][co128][ci32]
__global__ __launch_bounds__(256) void prep_w_k(const float* __restrict__ w,
                                                u16* __restrict__ wn) {
    const int co = blockIdx.x;
    const int t  = threadIdx.x;
    const float* wc = w + co * 3456;
    float s = 0.f;
    for (int i = t; i < 3456; i += 256) { float v = wc[i]; s += v * v; }
#pragma unroll
    for (int off = 32; off; off >>= 1) s += __shfl_down(s, off);
    __shared__ float red[4];
    __shared__ float dsh;
    if ((t & 63) == 0) red[t >> 6] = s;
    __syncthreads();
    if (t == 0) dsh = rsqrtf(red[0] + red[1] + red[2] + red[3] + 1e-8f);
    __syncthreads();
    const float d = dsh;
    for (int i = t; i < 3456; i += 256) {
        int ci = i / 27, tap = i - ci * 27;
        float v = wc[i] * d;
        wn[((tap * 4 + (ci >> 5)) * 128 + co) * 32 + (ci & 31)] = f2bf(v);
    }
}

// ---------------- Kernel 2: transpose x -> channels-grouped bf16 -------------
// xt[((b*16 + g)*32768 + d*1024 + h*32 + w)*8 + j] = bf16(x[b][g*8+j][d][h][w])
__global__ __launch_bounds__(256) void xpose_k(const float* __restrict__ x,
                                               u16* __restrict__ xt) {
    const int bid = blockIdx.x;
    const int b = bid >> 10, d = (bid >> 5) & 31, h = bid & 31;
    const int t = threadIdx.x;
    const int w = t & 31, cg = t >> 5;
    const int base_dhw = d * 1024 + h * 32 + w;
#pragma unroll
    for (int r = 0; r < 2; ++r) {
        int g = cg + r * 8;
        const float* src = x + ((size_t)(b * 128 + g * 8) << 15) + base_dhw;
        bf16x8 pk;
#pragma unroll
        for (int j = 0; j < 8; ++j) pk[j] = (short)f2bf(src[(size_t)j << 15]);
        *(bf16x8*)&xt[((size_t)((b * 16 + g) << 15) + base_dhw) * 8] = pk;
    }
}

// ---------------- Kernel 3: conv3d, 3-deep ring + counted vmcnt (T3/T4) ------
// 512 thr = 8 waves (4 M-slices x 2 co-halves). Tile M=256 (d2,h4,w32), N=128.
// LDS ring: 3 x (x 16KB + w 8KB) = 72 KB -> 2 blocks/CU.
// k-step: vmcnt(3) [buf k landed] -> s_barrier -> ds_read frags(buf k) ->
//         issue STAGE(buf k+2, 3x gload_lds) -> MFMA. Never vmcnt(0) mid-loop.
#define KSX 1048576   // shorts: x advance per cc (4 groups * 32768 * 8)
#define KSW 4096      // shorts: wn advance per k-step
#define RB  12288     // shorts: ring stride (8192 x + 4096 w)
__global__ __launch_bounds__(512, 4) void conv_mx(
    const u16* __restrict__ wsb, const float* __restrict__ bias,
    float* __restrict__ out) {
    __shared__ __align__(16) u16 lds[3 * RB];     // 73728 B
    const u16* xt = wsb + 524288;
    const u16* wn = wsb + 512;
    const u16* zp = wsb;                          // zero page (memset)

    const int t = threadIdx.x, lane = t & 63, wid = t >> 6;
    const int ll = lane & 15, g = lane >> 4;
    const int mslice = wid >> 1, ncol = wid & 1;

    int wg = ((blockIdx.x & 7) << 7) | (blockIdx.x >> 3);   // XCD swizzle
    const int b = wg >> 7, dt = (wg >> 3) & 15, ht = wg & 7;
    const int d0 = dt * 2, h0 = ht * 4;

    // loop-invariant ds_read offsets (shorts, within tile)
    const int pos0 = mslice * 64 + ll;
    const int xro = pos0 * 32 + ((g ^ ((pos0 >> 1) & 3)) * 8);
    const int co0 = ncol * 64 + ll;
    const int wro = co0 * 32 + ((g ^ ((co0 >> 1) & 3)) * 8);

    // staging lane constants
    const int posA = wid * 32 + (lane >> 2);
    const int slot = lane & 3;
    const int pdA = posA >> 7, phA = (posA >> 5) & 3, wA = posA & 31;
    const int gA = slot ^ ((posA >> 1) & 3);
    const int wco = wid * 16 + (lane >> 2);
    const u16* wsrc = wn + wco * 32 + ((slot ^ ((wco >> 1) & 3)) * 8);

    f32x4 acc[4][4];
#pragma unroll
    for (int i = 0; i < 4; ++i)
#pragma unroll
        for (int j = 0; j < 4; ++j) acc[i][j] = (f32x4){0.f, 0.f, 0.f, 0.f};

    // staging cursor (2 k-steps ahead of compute)
    int od_s = 0, oh_s = 0, ow_s = 0, cc_s = 0;
    const u16* xsA = xt; bool okA = false, okB = false;

#define DO_STAGE(SB) { \
    if (cc_s == 0) { \
        int Dx = d0 + pdA - 1 + od_s, Hx = h0 + phA - 1 + oh_s, Wx = wA - 1 + ow_s; \
        bool dh_ = ((unsigned)Dx < 32u) && ((unsigned)Hx < 32u); \
        okA = dh_ && ((unsigned)Wx < 32u); \
        okB = dh_ && (Wx < 16); \
        xsA = xt + (long)((b * 16 + gA) * 32768 + Dx * 1024 + Hx * 32 + Wx) * 8; } \
    gload_lds16(okA ? (const void*)xsA : (const void*)zp, (void*)&lds[(SB)*RB + wid*1024]); \
    gload_lds16(okB ? (const void*)(xsA + 128) : (const void*)zp, (void*)&lds[(SB)*RB + wid*1024 + 512]); \
    gload_lds16((const void*)wsrc, (void*)&lds[(SB)*RB + 8192 + wid*512]); \
    xsA += KSX; wsrc += KSW; \
    if (++cc_s == 4) { cc_s = 0; \
        if (++ow_s == 3) { ow_s = 0; if (++oh_s == 3) { oh_s = 0; ++od_s; } } } }

#define KSTEP(CB, SB, VMN, DOST) { \
    asm volatile("s_waitcnt vmcnt(" #VMN ")" ::: "memory"); \
    asm volatile("s_barrier" ::: "memory"); \
    bf16x8 xf[4], wf[4]; \
    _Pragma("unroll") for (int mf = 0; mf < 4; ++mf) \
        xf[mf] = *(const bf16x8*)&lds[(CB)*RB + xro + mf*512]; \
    _Pragma("unroll") for (int nf = 0; nf < 4; ++nf) \
        wf[nf] = *(const bf16x8*)&lds[(CB)*RB + 8192 + wro + nf*512]; \
    if (DOST) DO_STAGE(SB); \
    __builtin_amdgcn_s_setprio(1); \
    _Pragma("unroll") for (int mf = 0; mf < 4; ++mf) \
    _Pragma("unroll") for (int nf = 0; nf < 4; ++nf) \
        acc[mf][nf] = __builtin_amdgcn_mfma_f32_16x16x32_bf16(wf[nf], xf[mf], acc[mf][nf], 0, 0, 0); \
    __builtin_amdgcn_s_setprio(0); }

    // prologue: stage k=0 -> buf0, k=1 -> buf1 (6 loads in flight)
    DO_STAGE(0);
    DO_STAGE(1);

    for (int m = 0; m < 35; ++m) {      // k = 0..104
        KSTEP(0, 2, 3, 1);
        KSTEP(1, 0, 3, 1);
        KSTEP(2, 1, 3, 1);
    }
    KSTEP(0, 2, 3, 1);                  // k=105, stages k=107 -> buf2
    KSTEP(1, 0, 3, 0);                  // k=106
    KSTEP(2, 0, 0, 0);                  // k=107, full drain

    // epilogue: bias + leaky_relu + sqrt(2) + clamp, direct stores
    const int pd = mslice >> 1, phb = (mslice & 1) * 2;
#pragma unroll
    for (int nf = 0; nf < 4; ++nf) {
        f32x4 bb = *(const f32x4*)&bias[ncol * 64 + nf * 16 + g * 4];
#pragma unroll
        for (int mf = 0; mf < 4; ++mf) {
            const int wq = (mf & 1) * 16 + ll;
            const int hh = h0 + phb + (mf >> 1);
            float* orow = out + ((size_t)(b * 128 + ncol * 64 + nf * 16 + g * 4) << 15)
                          + (d0 + pd) * 1024 + hh * 32 + wq;
#pragma unroll
            for (int q = 0; q < 4; ++q) {
                float v = acc[mf][nf][q] + bb[q];
                v = v > 0.f ? v : v * 0.2f;
                v *= 1.41421356237f;
                v = fminf(fmaxf(v, -256.f), 256.f);
                orow[(size_t)q << 15] = v;
            }
        }
    }
#undef DO_STAGE
#undef KSTEP
}

// ---------------- Fallback conv (R4, proven) if ws too small -----------------
#define NPOS 544
__global__ __launch_bounds__(256, 4) void conv_fb(
    const float* __restrict__ x, const u16* __restrict__ wn,
    const float* __restrict__ bias, float* __restrict__ out) {
    __shared__ __align__(16) u16 lds[NPOS * 32];
    float* ldsf = reinterpret_cast<float*>(lds);
    const int t = threadIdx.x;
    const int lane = t & 63;
    const int wid  = t >> 6;
    const int wr   = wid >> 1;
    const int wcn  = wid & 1;
    const int ll   = lane & 15;
    const int g    = lane >> 4;
    const int bid = blockIdx.x;
    const int b  = bid >> 8;
    const int dt = (bid >> 4) & 15, ht = bid & 15;
    const int d0 = dt * 2, h0 = ht * 2;
    const int sw  = t & 31;
    const int sg  = (t >> 5) & 3;
    const int rhi = t >> 7;
    f32x4 acc[4][4];
#pragma unroll
    for (int i = 0; i < 4; ++i)
#pragma unroll
        for (int j = 0; j < 4; ++j) acc[i][j] = (f32x4){0.f, 0.f, 0.f, 0.f};
    float bv[4][4];
#pragma unroll
    for (int nf = 0; nf < 4; ++nf) {
        f32x4 bb = *(const f32x4*)&bias[wcn * 64 + nf * 16 + g * 4];
#pragma unroll
        for (int q = 0; q < 4; ++q) bv[nf][q] = bb[q];
    }
    if (t < 128) {
        int pi  = t >> 2;
        int row = pi >> 1;
        int pos = row * 34 + (pi & 1) * 33;
        bf16x8 z = {0, 0, 0, 0, 0, 0, 0, 0};
        *(bf16x8*)&lds[pos * 32 + (t & 3) * 8] = z;
    }
    for (int c = 0; c < 4; ++c) {
        if (c) __syncthreads();
#pragma unroll
        for (int p = 0; p < 8; ++p) {
            int rowid = p * 2 + rhi;
            int pd = rowid >> 2, ph = rowid & 3;
            int d = d0 - 1 + pd, h = h0 - 1 + ph;
            bool ok = ((unsigned)d < 32u) && ((unsigned)h < 32u);
            const float* src = x + (((b * 128 + c * 32 + sg * 8) * 32 + d) * 32 + h) * 32 + sw;
            float v[8];
#pragma unroll
            for (int j = 0; j < 8; ++j) v[j] = ok ? src[j * 32768] : 0.f;
            bf16x8 pk;
#pragma unroll
            for (int j = 0; j < 8; ++j) pk[j] = (short)f2bf(v[j]);
            int pos = rowid * 34 + sw + 1;
            int sl = sg ^ ((pos >> 1) & 3);
            *(bf16x8*)&lds[pos * 32 + sl * 8] = pk;
        }
        __syncthreads();
        const u16* wbase = wn + c * 4096 + ((wcn * 64 + ll) * 32 + g * 8);
        bf16x8 wf[4];
#pragma unroll
        for (int nf = 0; nf < 4; ++nf) wf[nf] = *(const bf16x8*)&wbase[nf * 512];
#pragma unroll
        for (int tap = 0; tap < 27; ++tap) {
            const int od = tap / 9, oh = (tap / 3) % 3, ow = tap % 3;
            bf16x8 wfn[4];
            if (tap < 26) {
#pragma unroll
                for (int nf = 0; nf < 4; ++nf)
                    wfn[nf] = *(const bf16x8*)&wbase[(tap + 1) * 16384 + nf * 512];
            }
            bf16x8 xf[4];
#pragma unroll
            for (int mf = 0; mf < 4; ++mf) {
                int pos = ((wr + od) * 4 + (mf >> 1) + oh) * 34 + (mf & 1) * 16 + ll + ow;
                int sl = g ^ ((pos >> 1) & 3);
                xf[mf] = *(const bf16x8*)&lds[pos * 32 + sl * 8];
            }
            __builtin_amdgcn_s_setprio(1);
#pragma unroll
            for (int mf = 0; mf < 4; ++mf)
#pragma unroll
                for (int nf = 0; nf < 4; ++nf)
                    acc[mf][nf] = __builtin_amdgcn_mfma_f32_16x16x32_bf16(
                        wf[nf], xf[mf], acc[mf][nf], 0, 0, 0);
            __builtin_amdgcn_s_setprio(0);
            if (tap < 26) {
#pragma unroll
                for (int nf = 0; nf < 4; ++nf) wf[nf] = wfn[nf];
            }
        }
    }
#pragma unroll
    for (int p = 0; p < 4; ++p) {
        const int dd = p >> 1, hh = p & 1;
        __syncthreads();
        if (wr == dd) {
#pragma unroll
            for (int whalf = 0; whalf < 2; ++whalf) {
                const int mf = hh * 2 + whalf;
#pragma unroll
                for (int nf = 0; nf < 4; ++nf) {
#pragma unroll
                    for (int q = 0; q < 4; ++q) {
                        const int co = wcn * 64 + nf * 16 + g * 4 + q;
                        float v = acc[mf][nf][q] + bv[nf][q];
                        v = v > 0.f ? v : v * 0.2f;
                        v *= 1.41421356237f;
                        v = fminf(fmaxf(v, -256.f), 256.f);
                        ldsf[co * 33 + whalf * 16 + ll] = v;
                    }
                }
            }
        }
        __syncthreads();
#pragma unroll
        for (int it = 0; it < 4; ++it) {
            const int row = it * 32 + (t >> 3);
            const int ls  = t & 7;
            f32x4 v = *(f32x4*)&ldsf[row * 33 + ls * 4];
            *(f32x4*)&out[(size_t)(b * 128 + row) * 32768 +
                          (d0 + dd) * 1024 + (h0 + hh) * 32 + ls * 4] = v;
        }
    }
}

extern "C" void kernel_launch(void* const* d_in, const int* in_sizes, int n_in,
                              void* d_out, int out_size, void* d_ws, size_t ws_size,
                              hipStream_t stream) {
    const float* x    = (const float*)d_in[0];
    const float* w    = (const float*)d_in[1];
    const float* bias = (const float*)d_in[2];
    float* out        = (float*)d_out;
    u16* wsb          = (u16*)d_ws;

    hipMemsetAsync(d_ws, 0, 1024, stream);                 // zero page
    prep_w_k<<<128, 256, 0, stream>>>(w, wsb + 512);       // wn at +1KB

    if (ws_size >= 68157440ull) {
        xpose_k<<<8192, 256, 0, stream>>>(x, wsb + 524288);  // xt at +1MB
        conv_mx<<<1024, 512, 0, stream>>>(wsb, bias, out);
    } else {
        conv_fb<<<2048, 256, 0, stream>>>(x, wsb + 512, bias, out);
    }
}

// Round 7
// 292.805 us; speedup vs baseline: 2.6357x; 1.0115x over previous
//
#include <hip/hip_runtime.h>

typedef short bf16x8 __attribute__((ext_vector_type(8)));
typedef float f32x4  __attribute__((ext_vector_type(4)));
typedef unsigned short u16;

static __device__ __forceinline__ u16 f2bf(float f) {
    unsigned int u = __builtin_bit_cast(unsigned int, f);
    u += 0x7FFFu + ((u >> 16) & 1u);   // round-to-nearest-even
    return (u16)(u >> 16);
}

static __device__ __forceinline__ void gload_lds16(const void* g, void* l) {
    __builtin_amdgcn_global_load_lds((const __attribute__((address_space(1))) void*)g,
                                     (__attribute__((address_space(3))) void*)l, 16, 0, 0);
}

// ---------------- Kernel 1: demodulate + convert weights to bf16 -------------
// wn[((tap*4 + cc)*128 + co)*32 + ci_in_chunk]  == kstep-major [k108][co128][ci32]
__global__ __launch_bounds__(256) void prep_w_k(const float* __restrict__ w,
                                                u16* __restrict__ wn) {
    const int co = blockIdx.x;
    const int t  = threadIdx.x;
    const float* wc = w + co * 3456;
    float s = 0.f;
    for (int i = t; i < 3456; i += 256) { float v = wc[i]; s += v * v; }
#pragma unroll
    for (int off = 32; off; off >>= 1) s += __shfl_down(s, off);
    __shared__ float red[4];
    __shared__ float dsh;
    if ((t & 63) == 0) red[t >> 6] = s;
    __syncthreads();
    if (t == 0) dsh = rsqrtf(red[0] + red[1] + red[2] + red[3] + 1e-8f);
    __syncthreads();
    const float d = dsh;
    for (int i = t; i < 3456; i += 256) {
        int ci = i / 27, tap = i - ci * 27;
        float v = wc[i] * d;
        wn[((tap * 4 + (ci >> 5)) * 128 + co) * 32 + (ci & 31)] = f2bf(v);
    }
}

// ---------------- Kernel 2: transpose x -> channels-grouped bf16 -------------
// xt[((b*16 + g)*32768 + d*1024 + h*32 + w)*8 + j] = bf16(x[b][g*8+j][d][h][w])
__global__ __launch_bounds__(256) void xpose_k(const float* __restrict__ x,
                                               u16* __restrict__ xt) {
    const int bid = blockIdx.x;
    const int b = bid >> 10, d = (bid >> 5) & 31, h = bid & 31;
    const int t = threadIdx.x;
    const int w = t & 31, cg = t >> 5;
    const int base_dhw = d * 1024 + h * 32 + w;
#pragma unroll
    for (int r = 0; r < 2; ++r) {
        int g = cg + r * 8;
        const float* src = x + ((size_t)(b * 128 + g * 8) << 15) + base_dhw;
        bf16x8 pk;
#pragma unroll
        for (int j = 0; j < 8; ++j) pk[j] = (short)f2bf(src[(size_t)j << 15]);
        *(bf16x8*)&xt[((size_t)((b * 16 + g) << 15) + base_dhw) * 8] = pk;
    }
}

// ---------------- Kernel 3: conv3d, overlapped ring pipeline -----------------
// 256 thr = 4 waves (2 d-slices x 2 co-halves). Tile M=256 (d2,h4,w32), N=128.
// Wave tile 128x64: acc 8x4 f32x4 = 128 regs; 2 blocks/CU (2 waves/SIMD).
// LDS ring: 3 x (x 16KB + w 8KB) = 72 KB/block.
// Step k: ds_read frags(k) -> issue stage(k+2) -> MFMA(k) (lgkm-interleaved by
// compiler) -> vmcnt(6) [retire st(k+1)] -> s_barrier. Reads overlap MFMA.
#define KSX 1048576   // shorts: x advance per cc (4 groups * 32768 * 8)
#define KSW 4096      // shorts: wn advance per k-step
#define RB  12288     // shorts: ring stride (8192 x + 4096 w)
__global__ __launch_bounds__(256, 2) void conv_mx(
    const u16* __restrict__ wsb, const float* __restrict__ bias,
    float* __restrict__ out) {
    __shared__ __align__(16) u16 lds[3 * RB];     // 73728 B
    const u16* xt = wsb + 524288;
    const u16* wn = wsb + 512;
    const u16* zp = wsb;                          // zero page (memset)

    const int t = threadIdx.x, lane = t & 63, wid = t >> 6;
    const int ll = lane & 15, g = lane >> 4;
    const int mslice = wid >> 1, ncol = wid & 1;

    int wg = ((blockIdx.x & 7) << 7) | (blockIdx.x >> 3);   // XCD swizzle
    const int b = wg >> 7, dt = (wg >> 3) & 15, ht = wg & 7;
    const int d0 = dt * 2, h0 = ht * 4;

    // loop-invariant ds_read offsets (shorts, within ring buffer)
    const int slotr = g ^ ((ll >> 1) & 3);
    const int xro = (mslice * 128 + ll) * 32 + slotr * 8;
    const int wro = 8192 + (ncol * 64 + ll) * 32 + slotr * 8;

    // staging lane constants: 4 x-gloads + 2 w-gloads per thread per k-step
    const int gA = (lane & 3) ^ ((lane >> 3) & 3);
    int pdl[4], phl[4], pwl[4];
#pragma unroll
    for (int i = 0; i < 4; ++i) {
        int p = (wid * 4 + i) * 16 + (lane >> 2);
        pdl[i] = p >> 7; phl[i] = (p >> 5) & 3; pwl[i] = p & 31;
    }
    const u16* wsrc0 = wn + ((wid * 2) * 16 + (lane >> 2)) * 32 + gA * 8;
    const u16* wsrc1 = wsrc0 + 512;

    f32x4 acc[8][4];
#pragma unroll
    for (int i = 0; i < 8; ++i)
#pragma unroll
        for (int j = 0; j < 4; ++j) acc[i][j] = (f32x4){0.f, 0.f, 0.f, 0.f};

    // staging cursor (2 k-steps ahead of compute)
    int od_s = 0, oh_s = 0, ow_s = 0, cc_s = 0;
    const u16* xs[4]; int okl[4];

#define DO_STAGE(SB) { \
    if (cc_s == 0) { \
        _Pragma("unroll") for (int i = 0; i < 4; ++i) { \
            int Dx = d0 + pdl[i] - 1 + od_s, Hx = h0 + phl[i] - 1 + oh_s, Wx = pwl[i] - 1 + ow_s; \
            okl[i] = (((unsigned)Dx < 32u) && ((unsigned)Hx < 32u) && ((unsigned)Wx < 32u)) ? 1 : 0; \
            xs[i] = xt + (long)((b * 16 + gA) * 32768 + Dx * 1024 + Hx * 32 + Wx) * 8; } } \
    _Pragma("unroll") for (int i = 0; i < 4; ++i) \
        gload_lds16(okl[i] ? (const void*)xs[i] : (const void*)zp, \
                    (void*)&lds[(SB)*RB + (wid * 4 + i) * 512]); \
    gload_lds16((const void*)wsrc0, (void*)&lds[(SB)*RB + 8192 + wid * 1024]); \
    gload_lds16((const void*)wsrc1, (void*)&lds[(SB)*RB + 8192 + wid * 1024 + 512]); \
    _Pragma("unroll") for (int i = 0; i < 4; ++i) xs[i] += KSX; \
    wsrc0 += KSW; wsrc1 += KSW; \
    if (++cc_s == 4) { cc_s = 0; \
        if (++ow_s == 3) { ow_s = 0; if (++oh_s == 3) { oh_s = 0; ++od_s; } } } }

#define KSTEP(CB, SB, DOST, VMSTR, DOBAR) { \
    bf16x8 wf[4], xf[8]; \
    _Pragma("unroll") for (int nf = 0; nf < 4; ++nf) \
        wf[nf] = *(const bf16x8*)&lds[(CB)*RB + wro + nf * 512]; \
    _Pragma("unroll") for (int mf = 0; mf < 8; ++mf) \
        xf[mf] = *(const bf16x8*)&lds[(CB)*RB + xro + mf * 512]; \
    if (DOST) DO_STAGE(SB); \
    __builtin_amdgcn_s_setprio(1); \
    _Pragma("unroll") for (int mf = 0; mf < 8; ++mf) \
    _Pragma("unroll") for (int nf = 0; nf < 4; ++nf) \
        acc[mf][nf] = __builtin_amdgcn_mfma_f32_16x16x32_bf16(wf[nf], xf[mf], acc[mf][nf], 0, 0, 0); \
    __builtin_amdgcn_s_setprio(0); \
    if (DOBAR) { \
        asm volatile("s_waitcnt " VMSTR ::: "memory"); \
        asm volatile("s_barrier" ::: "memory"); } }

    // prologue: stage k=0 -> buf0, k=1 -> buf1 (12 loads in flight)
    DO_STAGE(0);
    DO_STAGE(1);
    asm volatile("s_waitcnt vmcnt(6)" ::: "memory");   // buf0 landed (mine)
    asm volatile("s_barrier" ::: "memory");            // everyone's buf0 landed

    for (int m = 0; m < 35; ++m) {      // k = 0..104
        KSTEP(0, 2, 1, "vmcnt(6)", 1);
        KSTEP(1, 0, 1, "vmcnt(6)", 1);
        KSTEP(2, 1, 1, "vmcnt(6)", 1);
    }
    KSTEP(0, 2, 1, "vmcnt(6)", 1);      // k=105, stages k=107 -> buf2
    KSTEP(1, 0, 0, "vmcnt(0)", 1);      // k=106, drain st(107)
    KSTEP(2, 0, 0, "vmcnt(0)", 0);      // k=107, no tail sync

    // epilogue: bias + leaky_relu + sqrt(2) + clamp, direct stores
    const int dd = d0 + mslice;
#pragma unroll
    for (int nf = 0; nf < 4; ++nf) {
        f32x4 bb = *(const f32x4*)&bias[ncol * 64 + nf * 16 + g * 4];
#pragma unroll
        for (int mf = 0; mf < 8; ++mf) {
            const int wq = (mf & 1) * 16 + ll;
            const int hh = h0 + (mf >> 1);
            float* orow = out + ((size_t)(b * 128 + ncol * 64 + nf * 16 + g * 4) << 15)
                          + dd * 1024 + hh * 32 + wq;
#pragma unroll
            for (int q = 0; q < 4; ++q) {
                float v = acc[mf][nf][q] + bb[q];
                v = v > 0.f ? v : v * 0.2f;
                v *= 1.41421356237f;
                v = fminf(fmaxf(v, -256.f), 256.f);
                orow[(size_t)q << 15] = v;
            }
        }
    }
#undef DO_STAGE
#undef KSTEP
}

// ---------------- Fallback conv (R4, proven) if ws too small -----------------
#define NPOS 544
__global__ __launch_bounds__(256, 4) void conv_fb(
    const float* __restrict__ x, const u16* __restrict__ wn,
    const float* __restrict__ bias, float* __restrict__ out) {
    __shared__ __align__(16) u16 lds[NPOS * 32];
    float* ldsf = reinterpret_cast<float*>(lds);
    const int t = threadIdx.x;
    const int lane = t & 63;
    const int wid  = t >> 6;
    const int wr   = wid >> 1;
    const int wcn  = wid & 1;
    const int ll   = lane & 15;
    const int g    = lane >> 4;
    const int bid = blockIdx.x;
    const int b  = bid >> 8;
    const int dt = (bid >> 4) & 15, ht = bid & 15;
    const int d0 = dt * 2, h0 = ht * 2;
    const int sw  = t & 31;
    const int sg  = (t >> 5) & 3;
    const int rhi = t >> 7;
    f32x4 acc[4][4];
#pragma unroll
    for (int i = 0; i < 4; ++i)
#pragma unroll
        for (int j = 0; j < 4; ++j) acc[i][j] = (f32x4){0.f, 0.f, 0.f, 0.f};
    float bv[4][4];
#pragma unroll
    for (int nf = 0; nf < 4; ++nf) {
        f32x4 bb = *(const f32x4*)&bias[wcn * 64 + nf * 16 + g * 4];
#pragma unroll
        for (int q = 0; q < 4; ++q) bv[nf][q] = bb[q];
    }
    if (t < 128) {
        int pi  = t >> 2;
        int row = pi >> 1;
        int pos = row * 34 + (pi & 1) * 33;
        bf16x8 z = {0, 0, 0, 0, 0, 0, 0, 0};
        *(bf16x8*)&lds[pos * 32 + (t & 3) * 8] = z;
    }
    for (int c = 0; c < 4; ++c) {
        if (c) __syncthreads();
#pragma unroll
        for (int p = 0; p < 8; ++p) {
            int rowid = p * 2 + rhi;
            int pd = rowid >> 2, ph = rowid & 3;
            int d = d0 - 1 + pd, h = h0 - 1 + ph;
            bool ok = ((unsigned)d < 32u) && ((unsigned)h < 32u);
            const float* src = x + (((b * 128 + c * 32 + sg * 8) * 32 + d) * 32 + h) * 32 + sw;
            float v[8];
#pragma unroll
            for (int j = 0; j < 8; ++j) v[j] = ok ? src[j * 32768] : 0.f;
            bf16x8 pk;
#pragma unroll
            for (int j = 0; j < 8; ++j) pk[j] = (short)f2bf(v[j]);
            int pos = rowid * 34 + sw + 1;
            int sl = sg ^ ((pos >> 1) & 3);
            *(bf16x8*)&lds[pos * 32 + sl * 8] = pk;
        }
        __syncthreads();
        const u16* wbase = wn + c * 4096 + ((wcn * 64 + ll) * 32 + g * 8);
        bf16x8 wf[4];
#pragma unroll
        for (int nf = 0; nf < 4; ++nf) wf[nf] = *(const bf16x8*)&wbase[nf * 512];
#pragma unroll
        for (int tap = 0; tap < 27; ++tap) {
            const int od = tap / 9, oh = (tap / 3) % 3, ow = tap % 3;
            bf16x8 wfn[4];
            if (tap < 26) {
#pragma unroll
                for (int nf = 0; nf < 4; ++nf)
                    wfn[nf] = *(const bf16x8*)&wbase[(tap + 1) * 16384 + nf * 512];
            }
            bf16x8 xf[4];
#pragma unroll
            for (int mf = 0; mf < 4; ++mf) {
                int pos = ((wr + od) * 4 + (mf >> 1) + oh) * 34 + (mf & 1) * 16 + ll + ow;
                int sl = g ^ ((pos >> 1) & 3);
                xf[mf] = *(const bf16x8*)&lds[pos * 32 + sl * 8];
            }
            __builtin_amdgcn_s_setprio(1);
#pragma unroll
            for (int mf = 0; mf < 4; ++mf)
#pragma unroll
                for (int nf = 0; nf < 4; ++nf)
                    acc[mf][nf] = __builtin_amdgcn_mfma_f32_16x16x32_bf16(
                        wf[nf], xf[mf], acc[mf][nf], 0, 0, 0);
            __builtin_amdgcn_s_setprio(0);
            if (tap < 26) {
#pragma unroll
                for (int nf = 0; nf < 4; ++nf) wf[nf] = wfn[nf];
            }
        }
    }
#pragma unroll
    for (int p = 0; p < 4; ++p) {
        const int dd = p >> 1, hh = p & 1;
        __syncthreads();
        if (wr == dd) {
#pragma unroll
            for (int whalf = 0; whalf < 2; ++whalf) {
                const int mf = hh * 2 + whalf;
#pragma unroll
                for (int nf = 0; nf < 4; ++nf) {
#pragma unroll
                    for (int q = 0; q < 4; ++q) {
                        const int co = wcn * 64 + nf * 16 + g * 4 + q;
                        float v = acc[mf][nf][q] + bv[nf][q];
                        v = v > 0.f ? v : v * 0.2f;
                        v *= 1.41421356237f;
                        v = fminf(fmaxf(v, -256.f), 256.f);
                        ldsf[co * 33 + whalf * 16 + ll] = v;
                    }
                }
            }
        }
        __syncthreads();
#pragma unroll
        for (int it = 0; it < 4; ++it) {
            const int row = it * 32 + (t >> 3);
            const int ls  = t & 7;
            f32x4 v = *(f32x4*)&ldsf[row * 33 + ls * 4];
            *(f32x4*)&out[(size_t)(b * 128 + row) * 32768 +
                          (d0 + dd) * 1024 + (h0 + hh) * 32 + ls * 4] = v;
        }
    }
}

extern "C" void kernel_launch(void* const* d_in, const int* in_sizes, int n_in,
                              void* d_out, int out_size, void* d_ws, size_t ws_size,
                              hipStream_t stream) {
    const float* x    = (const float*)d_in[0];
    const float* w    = (const float*)d_in[1];
    const float* bias = (const float*)d_in[2];
    float* out        = (float*)d_out;
    u16* wsb          = (u16*)d_ws;

    hipMemsetAsync(d_ws, 0, 1024, stream);                 // zero page
    prep_w_k<<<128, 256, 0, stream>>>(w, wsb + 512);       // wn at +1KB

    if (ws_size >= 68157440ull) {
        xpose_k<<<8192, 256, 0, stream>>>(x, wsb + 524288);  // xt at +1MB
        conv_mx<<<1024, 256, 0, stream>>>(wsb, bias, out);
    } else {
        conv_fb<<<2048, 256, 0, stream>>>(x, wsb + 512, bias, out);
    }
}